// Round 3
// baseline (1676.532 us; speedup 1.0000x reference)
//
#include <hip/hip_runtime.h>
#include <math.h>

constexpr int   NGc    = 128;
constexpr int   NCELL  = NGc * NGc;
constexpr int   NBIN   = 128 * 32;          // bin = (bx, by>>2) : 4096
constexpr float DTc    = 1e-4f;
constexpr float DXc    = 1.0f / 128.0f;
constexpr float INV_DX = 128.0f;
constexpr float P_VOLc = (DXc * 0.5f) * (DXc * 0.5f);
constexpr float P_MASSc = P_VOLc * 1.0f;
constexpr float GRAV   = 9.8f;
constexpr float STRESS_COEF = -DTc * P_VOLc * 4.0f * INV_DX * INV_DX;

// ---------------------------------------------------------------------------
// S1: bin to 4096 bins (cell-row x col-group). LDS hist + local rank ->
// key = bin<<20 | pos_in_bin.
// ---------------------------------------------------------------------------
constexpr int S1_PPT = 16;
constexpr int S1_BLK = 1024;

__global__ __launch_bounds__(1024) void bin_kernel(
    const float2* __restrict__ x, unsigned* __restrict__ key,
    unsigned* __restrict__ gcnt, int n)
{
    __shared__ unsigned hist[NBIN];
#pragma unroll
    for (int j = 0; j < NBIN / S1_BLK; j++)
        hist[threadIdx.x + j * S1_BLK] = 0;
    __syncthreads();

    int base_i = blockIdx.x * (S1_BLK * S1_PPT);
    unsigned t_arr[S1_PPT], r_arr[S1_PPT];
#pragma unroll
    for (int k = 0; k < S1_PPT; k++) {
        int i = base_i + k * S1_BLK + threadIdx.x;
        unsigned t = 0, r = 0;
        if (i < n) {
            float2 xi = x[i];
            int bx = (int)floorf(xi.x * INV_DX - 0.5f);
            int by = (int)floorf(xi.y * INV_DX - 0.5f);
            t = (unsigned)(bx * 32 + (by >> 2));
            r = atomicAdd(&hist[t], 1u);
        }
        t_arr[k] = t; r_arr[k] = r;
    }
    __syncthreads();

#pragma unroll
    for (int j = 0; j < NBIN / S1_BLK; j++) {
        int b = threadIdx.x + j * S1_BLK;
        unsigned c = hist[b];
        __syncthreads();
        hist[b] = c ? atomicAdd(&gcnt[b], c) : 0u;
        __syncthreads();
    }

#pragma unroll
    for (int k = 0; k < S1_PPT; k++) {
        int i = base_i + k * S1_BLK + threadIdx.x;
        if (i < n)
            key[i] = (t_arr[k] << 20) | (hist[t_arr[k]] + r_arr[k]);
    }
}

// ---------------------------------------------------------------------------
// S2: exclusive scan over 4096 bin counts (single block, 4/thread) + sentinel
// ---------------------------------------------------------------------------
__global__ __launch_bounds__(1024) void scan_kernel(
    const unsigned* __restrict__ gcnt, unsigned* __restrict__ binoff)
{
    __shared__ unsigned s[1024];
    int t = threadIdx.x;
    unsigned v0 = gcnt[4 * t], v1 = gcnt[4 * t + 1];
    unsigned v2 = gcnt[4 * t + 2], v3 = gcnt[4 * t + 3];
    unsigned p = v0 + v1 + v2 + v3;
    s[t] = p;
    __syncthreads();
    for (int d = 1; d < 1024; d <<= 1) {
        unsigned add = (t >= d) ? s[t - d] : 0u;
        __syncthreads();
        s[t] += add;
        __syncthreads();
    }
    unsigned base = s[t] - p;
    binoff[4 * t]     = base;
    binoff[4 * t + 1] = base + v0;
    binoff[4 * t + 2] = base + v0 + v1;
    binoff[4 * t + 3] = base + v0 + v1 + v2;
    if (t == 1023) binoff[4096] = s[1023];
}

// ---------------------------------------------------------------------------
// Stage A v3: NN stress, LDS weights, 2 particles/thread to halve the
// wave-uniform ds_read_b128 count per particle (DS-throughput-bound: 256
// b128 * ~12cyc * ~61 waves/CU ~= 78us == R0's 80us; halving -> ~39us bound).
// Register-pressure engineering vs failed R2 (256 VGPR, 1.4GB spill traffic):
//   (a) ReLU masks as bitfields (m1/m2, 1 VGPR each) so h1 dies after L2
//       and h2 dies after L3 -> peak NN state 64 floats, not 128.
//   (b) Nothing else carried across the NN except feat0/feat1; x/C/F are
//       reloaded (L2-hot) and Fn/Cm/tr/delta recomputed in the epilogue.
// ---------------------------------------------------------------------------
constexpr int A_PPT = 2;

__global__ __launch_bounds__(256) void stagea_kernel(
    const float2* __restrict__ x, const float2* __restrict__ v,
    const float4* __restrict__ C, const float4* __restrict__ F,
    const float* __restrict__ W1, const float* __restrict__ b1,
    const float* __restrict__ W2, const float* __restrict__ b2,
    const float* __restrict__ W3, const float* __restrict__ b3,
    const float* __restrict__ W4,
    const unsigned* __restrict__ key, const unsigned* __restrict__ binoff,
    float4* __restrict__ recs, float4* __restrict__ out_F, int n)
{
    __shared__ float sW1[32];
    __shared__ float sW2[256], sW2T[256];
    __shared__ float sW3[256], sW3T[256];
    __shared__ float sb1[16], sb2[16], sb3[16], sW4[16];

    {
        int t = threadIdx.x;
        float w2 = W2[t], w3 = W3[t];
        sW2[t] = w2;  sW2T[(t & 15) * 16 + (t >> 4)] = w2;
        sW3[t] = w3;  sW3T[(t & 15) * 16 + (t >> 4)] = w3;
        if (t < 32) sW1[t] = W1[t];
        if (t < 16) { sb1[t] = b1[t]; sb2[t] = b2[t]; sb3[t] = b3[t]; sW4[t] = W4[t]; }
    }
    __syncthreads();

    const float4* W2r  = (const float4*)sW2;    // row j = W2r[4j .. 4j+3]
    const float4* W2Tr = (const float4*)sW2T;
    const float4* W3r  = (const float4*)sW3;
    const float4* W3Tr = (const float4*)sW3T;

    int base = blockIdx.x * (256 * A_PPT) + threadIdx.x;

    bool  ok[A_PPT];
    float feat0[A_PPT], feat1[A_PPT];

    // ---- Phase A: features + out_F (everything else dies here) ----
#pragma unroll
    for (int p = 0; p < A_PPT; p++) {
        int i = base + p * 256;
        ok[p] = (i < n);
        int ii = ok[p] ? i : 0;

        float4 Ci = C[ii];
        float4 Fi = F[ii];

        float Fn00 = Fi.x + DTc * (Ci.x * Fi.x + Ci.y * Fi.z);
        float Fn01 = Fi.y + DTc * (Ci.x * Fi.y + Ci.y * Fi.w);
        float Fn10 = Fi.z + DTc * (Ci.z * Fi.x + Ci.w * Fi.z);
        float Fn11 = Fi.w + DTc * (Ci.z * Fi.y + Ci.w * Fi.w);

        if (ok[p]) out_F[i] = make_float4(Fn00, Fn01, Fn10, Fn11);

        float Cm00 = Fn00 * Fn00 + Fn10 * Fn10;
        float Cm01 = Fn00 * Fn01 + Fn10 * Fn11;
        float Cm11 = Fn01 * Fn01 + Fn11 * Fn11;

        float tr  = Cm00 + Cm11;
        float det = Cm00 * Cm11 - Cm01 * Cm01;
        float g   = tr * tr - 4.0f * det;
        float delta = sqrtf(fmaxf(g, 1e-8f));
        feat0[p] = 0.5f * (tr + delta);
        feat1[p] = 0.5f * (tr - delta);
    }

    // ---- L1 ----
    float h1[A_PPT][16];
    unsigned m1[A_PPT];
#pragma unroll
    for (int p = 0; p < A_PPT; p++) m1[p] = 0u;
#pragma unroll
    for (int j = 0; j < 16; j++) {
        float wa = sW1[2 * j], wb = sW1[2 * j + 1], bb = sb1[j];
#pragma unroll
        for (int p = 0; p < A_PPT; p++) {
            float a = wa * feat0[p] + wb * feat1[p] + bb;
            m1[p] |= (a > 0.0f) ? (1u << j) : 0u;
            h1[p][j] = fmaxf(a, 0.0f);
        }
    }

    // ---- L2 (h1 dies at the end of this loop) ----
    float h2[A_PPT][16];
    unsigned m2[A_PPT];
#pragma unroll
    for (int p = 0; p < A_PPT; p++) m2[p] = 0u;
#pragma unroll
    for (int j = 0; j < 16; j++) {
        float4 w0 = W2r[4 * j], w1 = W2r[4 * j + 1], w2 = W2r[4 * j + 2], w3 = W2r[4 * j + 3];
        float bb = sb2[j];
#pragma unroll
        for (int p = 0; p < A_PPT; p++) {
            float a0 = w0.x * h1[p][0]  + w0.y * h1[p][1]  + w0.z * h1[p][2]  + w0.w * h1[p][3];
            float a1 = w1.x * h1[p][4]  + w1.y * h1[p][5]  + w1.z * h1[p][6]  + w1.w * h1[p][7];
            float a2 = w2.x * h1[p][8]  + w2.y * h1[p][9]  + w2.z * h1[p][10] + w2.w * h1[p][11];
            float a3 = w3.x * h1[p][12] + w3.y * h1[p][13] + w3.z * h1[p][14] + w3.w * h1[p][15];
            float a  = bb + ((a0 + a1) + (a2 + a3));
            m2[p] |= (a > 0.0f) ? (1u << j) : 0u;
            h2[p][j] = fmaxf(a, 0.0f);
        }
    }

    // ---- L3 fused with dh3 (h2 dies here; h3 never stored) ----
    float dh3[A_PPT][16];
#pragma unroll
    for (int j = 0; j < 16; j++) {
        float4 w0 = W3r[4 * j], w1 = W3r[4 * j + 1], w2 = W3r[4 * j + 2], w3 = W3r[4 * j + 3];
        float bb = sb3[j], w4j = sW4[j];
#pragma unroll
        for (int p = 0; p < A_PPT; p++) {
            float a0 = w0.x * h2[p][0]  + w0.y * h2[p][1]  + w0.z * h2[p][2]  + w0.w * h2[p][3];
            float a1 = w1.x * h2[p][4]  + w1.y * h2[p][5]  + w1.z * h2[p][6]  + w1.w * h2[p][7];
            float a2 = w2.x * h2[p][8]  + w2.y * h2[p][9]  + w2.z * h2[p][10] + w2.w * h2[p][11];
            float a3 = w3.x * h2[p][12] + w3.y * h2[p][13] + w3.z * h2[p][14] + w3.w * h2[p][15];
            float a = bb + ((a0 + a1) + (a2 + a3));
            dh3[p][j] = (a > 0.0f) ? w4j : 0.0f;
        }
    }

    // ---- Backward W3^T (dh3 dies here; gate via m2 bit test) ----
    float dh2[A_PPT][16];
#pragma unroll
    for (int kk = 0; kk < 16; kk++) {
        float4 w0 = W3Tr[4 * kk], w1 = W3Tr[4 * kk + 1], w2 = W3Tr[4 * kk + 2], w3 = W3Tr[4 * kk + 3];
#pragma unroll
        for (int p = 0; p < A_PPT; p++) {
            float a0 = w0.x * dh3[p][0]  + w0.y * dh3[p][1]  + w0.z * dh3[p][2]  + w0.w * dh3[p][3];
            float a1 = w1.x * dh3[p][4]  + w1.y * dh3[p][5]  + w1.z * dh3[p][6]  + w1.w * dh3[p][7];
            float a2 = w2.x * dh3[p][8]  + w2.y * dh3[p][9]  + w2.z * dh3[p][10] + w2.w * dh3[p][11];
            float a3 = w3.x * dh3[p][12] + w3.y * dh3[p][13] + w3.z * dh3[p][14] + w3.w * dh3[p][15];
            float a  = (a0 + a1) + (a2 + a3);
            dh2[p][kk] = ((m2[p] >> kk) & 1u) ? a : 0.0f;
        }
    }

    // ---- Backward W2^T + W1^T (gate via m1 bit test) ----
    float dfeat0[A_PPT], dfeat1[A_PPT];
#pragma unroll
    for (int p = 0; p < A_PPT; p++) { dfeat0[p] = 0.0f; dfeat1[p] = 0.0f; }

#pragma unroll
    for (int kk = 0; kk < 16; kk++) {
        float4 w0 = W2Tr[4 * kk], w1 = W2Tr[4 * kk + 1], w2 = W2Tr[4 * kk + 2], w3 = W2Tr[4 * kk + 3];
        float wa = sW1[2 * kk], wb = sW1[2 * kk + 1];
#pragma unroll
        for (int p = 0; p < A_PPT; p++) {
            float a0 = w0.x * dh2[p][0]  + w0.y * dh2[p][1]  + w0.z * dh2[p][2]  + w0.w * dh2[p][3];
            float a1 = w1.x * dh2[p][4]  + w1.y * dh2[p][5]  + w1.z * dh2[p][6]  + w1.w * dh2[p][7];
            float a2 = w2.x * dh2[p][8]  + w2.y * dh2[p][9]  + w2.z * dh2[p][10] + w2.w * dh2[p][11];
            float a3 = w3.x * dh2[p][12] + w3.y * dh2[p][13] + w3.z * dh2[p][14] + w3.w * dh2[p][15];
            float a  = (a0 + a1) + (a2 + a3);
            float dh1k = ((m1[p] >> kk) & 1u) ? a : 0.0f;
            dfeat0[p] += wa * dh1k;
            dfeat1[p] += wb * dh1k;
        }
    }

    // ---- Epilogue: reload x/C/F (L2-hot), recompute Fn/Cm/tr/delta, scatter ----
#pragma unroll
    for (int p = 0; p < A_PPT; p++) {
        if (!ok[p]) continue;
        int i = base + p * 256;

        float2 xi = x[i];
        float4 Ci = C[i];
        float4 Fi = F[i];

        float Fn00 = Fi.x + DTc * (Ci.x * Fi.x + Ci.y * Fi.z);
        float Fn01 = Fi.y + DTc * (Ci.x * Fi.y + Ci.y * Fi.w);
        float Fn10 = Fi.z + DTc * (Ci.z * Fi.x + Ci.w * Fi.z);
        float Fn11 = Fi.w + DTc * (Ci.z * Fi.y + Ci.w * Fi.w);

        float Cm00 = Fn00 * Fn00 + Fn10 * Fn10;
        float Cm01 = Fn00 * Fn01 + Fn10 * Fn11;
        float Cm11 = Fn01 * Fn01 + Fn11 * Fn11;

        float tr  = Cm00 + Cm11;
        float det = Cm00 * Cm11 - Cm01 * Cm01;
        float g   = tr * tr - 4.0f * det;
        float gate = (g > 1e-8f) ? 1.0f : 0.0f;
        float delta = sqrtf(fmaxf(g, 1e-8f));

        float half_sum  = 0.5f * (dfeat0[p] + dfeat1[p]);
        float half_diff = 0.5f * (dfeat0[p] - dfeat1[p]);
        float inv_delta = 1.0f / delta;
        float dtr  = half_sum + half_diff * tr * inv_delta * gate;
        float ddet = half_diff * (-2.0f) * inv_delta * gate;

        float S00 = 2.0f * (dtr + ddet * Cm11);
        float S11 = 2.0f * (dtr + ddet * Cm00);
        float S01 = -2.0f * ddet * Cm01;

        float dF00 = Fn00 * S00 + Fn01 * S01;
        float dF01 = Fn00 * S01 + Fn01 * S11;
        float dF10 = Fn10 * S00 + Fn11 * S01;
        float dF11 = Fn10 * S01 + Fn11 * S11;

        float a00 = STRESS_COEF * dF00 + P_MASSc * Ci.x;
        float a01 = STRESS_COEF * dF01 + P_MASSc * Ci.y;
        float a10 = STRESS_COEF * dF10 + P_MASSc * Ci.z;
        float a11 = STRESS_COEF * dF11 + P_MASSc * Ci.w;

        float2 vi = v[i];
        unsigned k = key[i];
        unsigned pos = binoff[k >> 20] + (k & 0xFFFFFu);

        recs[2 * (size_t)pos]     = make_float4(xi.x, xi.y, a00, a01);
        recs[2 * (size_t)pos + 1] = make_float4(a10, a11, P_MASSc * vi.x, P_MASSc * vi.y);
    }
}

// ---------------------------------------------------------------------------
// Gather-form grid build: one wave per grid node, register accumulate,
// butterfly reduce, fused grid update. No atomics.
// ---------------------------------------------------------------------------
__global__ __launch_bounds__(256) void grid_gather_kernel(
    const float4* __restrict__ recs, const unsigned* __restrict__ binoff,
    float2* __restrict__ gv)
{
    int wid  = threadIdx.x >> 6;
    int lane = threadIdx.x & 63;
    int node = blockIdx.x * 4 + wid;
    int gi = node >> 7;
    int gj = node & 127;

    const float gxx = (float)gi * DXc;
    const float gxy = (float)gj * DXc;

    float accx = 0.0f, accy = 0.0f, accm = 0.0f;

    int c0 = max(gj - 2, 0) >> 2;
    int c1 = min(gj, 127) >> 2;

#pragma unroll
    for (int r = 0; r < 3; r++) {
        int bx = gi - 2 + r;
        if (bx < 0 || bx > 127) continue;
        int lo = (int)binoff[bx * 32 + c0];
        int hi = (int)binoff[bx * 32 + c1 + 1];
        for (int k = lo + lane; k < hi; k += 64) {
            float4 r0 = recs[2 * (size_t)k];
            float4 r1 = recs[2 * (size_t)k + 1];

            float py = r0.y * INV_DX;
            int   by = (int)floorf(py - 0.5f);
            int   jj = gj - by;
            bool  ok = (jj >= 0) && (jj <= 2);

            float fy = py - (float)by;
            float fx = r0.x * INV_DX - (float)bx;

            float wx;
            if (r == 0)      wx = 0.5f * (fx - 0.5f) * (fx - 0.5f);   // ii = 2
            else if (r == 1) wx = 0.75f - (fx - 1.0f) * (fx - 1.0f);  // ii = 1
            else             wx = 0.5f * (1.5f - fx) * (1.5f - fx);   // ii = 0

            float wy0 = 0.5f * (1.5f - fy) * (1.5f - fy);
            float wy1 = 0.75f - (fy - 1.0f) * (fy - 1.0f);
            float wy2 = 0.5f * (fy - 0.5f) * (fy - 0.5f);
            float wy = (jj == 0) ? wy0 : ((jj == 1) ? wy1 : wy2);

            float wt = ok ? (wx * wy) : 0.0f;
            float dxp = gxx - r0.x;
            float dyp = gxy - r0.y;
            accx += wt * (r1.z + r0.z * dxp + r0.w * dyp);
            accy += wt * (r1.w + r1.x * dxp + r1.y * dyp);
            accm += wt * P_MASSc;
        }
    }

#pragma unroll
    for (int off = 32; off >= 1; off >>= 1) {
        accx += __shfl_xor(accx, off, 64);
        accy += __shfl_xor(accy, off, 64);
        accm += __shfl_xor(accm, off, 64);
    }

    if (lane == 0) {
        float vx = accx, vy = accy;
        if (accm > 0.0f) {
            float inv_m = 1.0f / accm;
            vx *= inv_m;
            vy *= inv_m;
        }
        vy -= DTc * GRAV;
        if (gi < 3)        vx = fmaxf(vx, 0.0f);
        if (gi >= NGc - 3) vx = fminf(vx, 0.0f);
        if (gj < 3)        vy = fmaxf(vy, 0.0f);
        if (gj >= NGc - 3) vy = fminf(vy, 0.0f);
        gv[node] = make_float2(vx, vy);
    }
}

// ---------------------------------------------------------------------------
// G2P (Fnew already written by stagea; no C/F reads here)
// ---------------------------------------------------------------------------
__global__ __launch_bounds__(256) void g2p_kernel(
    const float2* __restrict__ x, const float2* __restrict__ v,
    const int* __restrict__ material, const float* __restrict__ Jp,
    const float2* __restrict__ gv,
    float2* __restrict__ out_x, float2* __restrict__ out_v,
    float4* __restrict__ out_C,
    float* __restrict__ out_mat, float* __restrict__ out_Jp, int n)
{
    int i = blockIdx.x * 256 + threadIdx.x;
    if (i >= n) return;

    float2 xi = x[i];
    float2 vi = v[i];

    float px = xi.x * INV_DX, py = xi.y * INV_DX;
    int   bx = (int)floorf(px - 0.5f);
    int   by = (int)floorf(py - 0.5f);
    float fx = px - (float)bx;
    float fy = py - (float)by;
    float wxs[3] = {0.5f * (1.5f - fx) * (1.5f - fx),
                    0.75f - (fx - 1.0f) * (fx - 1.0f),
                    0.5f * (fx - 0.5f) * (fx - 0.5f)};
    float wys[3] = {0.5f * (1.5f - fy) * (1.5f - fy),
                    0.75f - (fy - 1.0f) * (fy - 1.0f),
                    0.5f * (fy - 0.5f) * (fy - 0.5f)};

    float accvx = 0.0f, accvy = 0.0f;
    float accC00 = 0.0f, accC01 = 0.0f, accC10 = 0.0f, accC11 = 0.0f;

#pragma unroll
    for (int ii = 0; ii < 3; ii++) {
        float gxx = (float)(bx + ii) * DXc;
#pragma unroll
        for (int jj = 0; jj < 3; jj++) {
            float wt = wxs[ii] * wys[jj];
            float2 gvn = gv[(bx + ii) * NGc + (by + jj)];
            float gxy = (float)(by + jj) * DXc;
            accvx  += wt * gvn.x;
            accvy  += wt * gvn.y;
            accC00 += wt * gvn.x * gxx;
            accC01 += wt * gvn.x * gxy;
            accC10 += wt * gvn.y * gxx;
            accC11 += wt * gvn.y * gxy;
        }
    }

    const float k4 = 4.0f * INV_DX * INV_DX;
    out_x[i]   = make_float2(xi.x + DTc * vi.x, xi.y + DTc * vi.y);
    out_v[i]   = make_float2(accvx, accvy);
    out_C[i]   = make_float4(k4 * (accC00 - accvx * xi.x),
                             k4 * (accC01 - accvx * xi.y),
                             k4 * (accC10 - accvy * xi.x),
                             k4 * (accC11 - accvy * xi.y));
    out_mat[i] = (float)material[i];
    out_Jp[i]  = Jp[i];
}

// ---------------------------------------------------------------------------
extern "C" void kernel_launch(void* const* d_in, const int* in_sizes, int n_in,
                              void* d_out, int out_size, void* d_ws, size_t ws_size,
                              hipStream_t stream)
{
    const float2* x  = (const float2*)d_in[0];
    const float2* v  = (const float2*)d_in[1];
    const float4* C  = (const float4*)d_in[2];
    const float4* F  = (const float4*)d_in[3];
    const int* material = (const int*)d_in[4];
    const float* Jp  = (const float*)d_in[5];
    const float* W1  = (const float*)d_in[8];
    const float* b1  = (const float*)d_in[9];
    const float* W2  = (const float*)d_in[10];
    const float* b2  = (const float*)d_in[11];
    const float* W3  = (const float*)d_in[12];
    const float* b3  = (const float*)d_in[13];
    const float* W4  = (const float*)d_in[14];

    const int n = in_sizes[0] / 2;

    // d_ws: gcnt (NBIN u32) + binoff (NBIN+1 u32) + gv (NCELL float2)
    unsigned* gcnt   = (unsigned*)d_ws;
    unsigned* binoff = gcnt + NBIN;
    float2*   gv     = (float2*)(binoff + NBIN + 1);

    float* out = (float*)d_out;
    float2* out_x   = (float2*)out;                    // 0..2N
    float2* out_v   = (float2*)(out + 2 * (size_t)n);  // 2N..4N
    float4* out_C   = (float4*)(out + 4 * (size_t)n);  // 4N..8N
    float4* out_F   = (float4*)(out + 8 * (size_t)n);  // 8N..12N  (written by stagea)
    float*  out_mat = out + 12 * (size_t)n;            // 12N..13N
    float*  out_Jp  = out + 13 * (size_t)n;            // 13N..14N

    // middle-phase scratch inside d_out (consumed before g2p overwrites):
    // recs occupies out[0..8N) = out_x/out_v/out_C regions, all written only
    // by g2p which runs after grid_gather has consumed recs.
    float4*   recs = (float4*)out;                     // 8N floats: 0..8N
    unsigned* key  = (unsigned*)out_mat;               // N u32:     12N..13N

    hipMemsetAsync(gcnt, 0, NBIN * sizeof(unsigned), stream);

    int s1_blocks = (n + S1_BLK * S1_PPT - 1) / (S1_BLK * S1_PPT);
    int blocks    = (n + 255) / 256;
    int a_blocks  = (n + 256 * A_PPT - 1) / (256 * A_PPT);
    bin_kernel<<<s1_blocks, S1_BLK, 0, stream>>>(x, key, gcnt, n);
    scan_kernel<<<1, 1024, 0, stream>>>(gcnt, binoff);
    stagea_kernel<<<a_blocks, 256, 0, stream>>>(x, v, C, F, W1, b1, W2, b2, W3, b3, W4,
                                                key, binoff, recs, out_F, n);
    grid_gather_kernel<<<NCELL / 4, 256, 0, stream>>>(recs, binoff, gv);
    g2p_kernel<<<blocks, 256, 0, stream>>>(x, v, material, Jp, gv,
                                           out_x, out_v, out_C, out_mat, out_Jp, n);
}

// Round 4
// 1602.331 us; speedup vs baseline: 1.0463x; 1.0463x over previous
//
#include <hip/hip_runtime.h>
#include <math.h>

constexpr int   NGc    = 128;
constexpr int   NCELL  = NGc * NGc;
constexpr int   NBIN   = 128 * 32;          // bin = (bx, by>>2) : 4096
constexpr float DTc    = 1e-4f;
constexpr float DXc    = 1.0f / 128.0f;
constexpr float INV_DX = 128.0f;
constexpr float P_VOLc = (DXc * 0.5f) * (DXc * 0.5f);
constexpr float P_MASSc = P_VOLc * 1.0f;
constexpr float GRAV   = 9.8f;
constexpr float STRESS_COEF = -DTc * P_VOLc * 4.0f * INV_DX * INV_DX;

// ---------------------------------------------------------------------------
// S1: bin to 4096 bins (cell-row x col-group). LDS hist + local rank ->
// key = bin<<20 | pos_in_bin.
// ---------------------------------------------------------------------------
constexpr int S1_PPT = 16;
constexpr int S1_BLK = 1024;

__global__ __launch_bounds__(1024) void bin_kernel(
    const float2* __restrict__ x, unsigned* __restrict__ key,
    unsigned* __restrict__ gcnt, int n)
{
    __shared__ unsigned hist[NBIN];
#pragma unroll
    for (int j = 0; j < NBIN / S1_BLK; j++)
        hist[threadIdx.x + j * S1_BLK] = 0;
    __syncthreads();

    int base_i = blockIdx.x * (S1_BLK * S1_PPT);
    unsigned t_arr[S1_PPT], r_arr[S1_PPT];
#pragma unroll
    for (int k = 0; k < S1_PPT; k++) {
        int i = base_i + k * S1_BLK + threadIdx.x;
        unsigned t = 0, r = 0;
        if (i < n) {
            float2 xi = x[i];
            int bx = (int)floorf(xi.x * INV_DX - 0.5f);
            int by = (int)floorf(xi.y * INV_DX - 0.5f);
            t = (unsigned)(bx * 32 + (by >> 2));
            r = atomicAdd(&hist[t], 1u);
        }
        t_arr[k] = t; r_arr[k] = r;
    }
    __syncthreads();

#pragma unroll
    for (int j = 0; j < NBIN / S1_BLK; j++) {
        int b = threadIdx.x + j * S1_BLK;
        unsigned c = hist[b];
        __syncthreads();
        hist[b] = c ? atomicAdd(&gcnt[b], c) : 0u;
        __syncthreads();
    }

#pragma unroll
    for (int k = 0; k < S1_PPT; k++) {
        int i = base_i + k * S1_BLK + threadIdx.x;
        if (i < n)
            key[i] = (t_arr[k] << 20) | (hist[t_arr[k]] + r_arr[k]);
    }
}

// ---------------------------------------------------------------------------
// S2: exclusive scan over 4096 bin counts (single block, 4/thread) + sentinel
// ---------------------------------------------------------------------------
__global__ __launch_bounds__(1024) void scan_kernel(
    const unsigned* __restrict__ gcnt, unsigned* __restrict__ binoff)
{
    __shared__ unsigned s[1024];
    int t = threadIdx.x;
    unsigned v0 = gcnt[4 * t], v1 = gcnt[4 * t + 1];
    unsigned v2 = gcnt[4 * t + 2], v3 = gcnt[4 * t + 3];
    unsigned p = v0 + v1 + v2 + v3;
    s[t] = p;
    __syncthreads();
    for (int d = 1; d < 1024; d <<= 1) {
        unsigned add = (t >= d) ? s[t - d] : 0u;
        __syncthreads();
        s[t] += add;
        __syncthreads();
    }
    unsigned base = s[t] - p;
    binoff[4 * t]     = base;
    binoff[4 * t + 1] = base + v0;
    binoff[4 * t + 2] = base + v0 + v1;
    binoff[4 * t + 3] = base + v0 + v1 + v2;
    if (t == 1023) binoff[4096] = s[1023];
}

// ---------------------------------------------------------------------------
// Stage A v4: NN stress, LDS weights, 2 particles/thread (halves the
// wave-uniform ds_read_b128 count per particle; DS pipe is the bound:
// 256 b128 * ~12cyc * waves/CU ~= R0's observed 80us).
// v2/v3 FAILURE DIAGNOSIS: 256 VGPR + GB-scale scratch traffic with only
// ~70 floats of algorithmic state  => LLVM pre-RA scheduler hoisted all 64
// ds_read_b128 of each unrolled pass (64 x float4 = 256 VGPRs of weights),
// then spilled the particle state. FIX: __builtin_amdgcn_sched_barrier(0)
// after every j-iteration pins the hoist window to 4 loads + 32 FMAs,
// reproducing R0's proven per-j schedule with double the FMAs per load.
// ---------------------------------------------------------------------------
constexpr int A_PPT = 2;

__global__ __launch_bounds__(256) void stagea_kernel(
    const float2* __restrict__ x, const float2* __restrict__ v,
    const float4* __restrict__ C, const float4* __restrict__ F,
    const float* __restrict__ W1, const float* __restrict__ b1,
    const float* __restrict__ W2, const float* __restrict__ b2,
    const float* __restrict__ W3, const float* __restrict__ b3,
    const float* __restrict__ W4,
    const unsigned* __restrict__ key, const unsigned* __restrict__ binoff,
    float4* __restrict__ recs, float4* __restrict__ out_F, int n)
{
    __shared__ float sW1[32];
    __shared__ float sW2[256], sW2T[256];
    __shared__ float sW3[256], sW3T[256];
    __shared__ float sb1[16], sb2[16], sb3[16], sW4[16];

    {
        int t = threadIdx.x;
        float w2 = W2[t], w3 = W3[t];
        sW2[t] = w2;  sW2T[(t & 15) * 16 + (t >> 4)] = w2;
        sW3[t] = w3;  sW3T[(t & 15) * 16 + (t >> 4)] = w3;
        if (t < 32) sW1[t] = W1[t];
        if (t < 16) { sb1[t] = b1[t]; sb2[t] = b2[t]; sb3[t] = b3[t]; sW4[t] = W4[t]; }
    }
    __syncthreads();

    const float4* W2r  = (const float4*)sW2;    // row j = W2r[4j .. 4j+3]
    const float4* W2Tr = (const float4*)sW2T;
    const float4* W3r  = (const float4*)sW3;
    const float4* W3Tr = (const float4*)sW3T;

    int base = blockIdx.x * (256 * A_PPT) + threadIdx.x;

    bool  ok[A_PPT];
    float feat0[A_PPT], feat1[A_PPT];

    // ---- Phase A: features + out_F (everything else dies here) ----
#pragma unroll
    for (int p = 0; p < A_PPT; p++) {
        int i = base + p * 256;
        ok[p] = (i < n);
        int ii = ok[p] ? i : 0;

        float4 Ci = C[ii];
        float4 Fi = F[ii];

        float Fn00 = Fi.x + DTc * (Ci.x * Fi.x + Ci.y * Fi.z);
        float Fn01 = Fi.y + DTc * (Ci.x * Fi.y + Ci.y * Fi.w);
        float Fn10 = Fi.z + DTc * (Ci.z * Fi.x + Ci.w * Fi.z);
        float Fn11 = Fi.w + DTc * (Ci.z * Fi.y + Ci.w * Fi.w);

        if (ok[p]) out_F[i] = make_float4(Fn00, Fn01, Fn10, Fn11);

        float Cm00 = Fn00 * Fn00 + Fn10 * Fn10;
        float Cm01 = Fn00 * Fn01 + Fn10 * Fn11;
        float Cm11 = Fn01 * Fn01 + Fn11 * Fn11;

        float tr  = Cm00 + Cm11;
        float det = Cm00 * Cm11 - Cm01 * Cm01;
        float g   = tr * tr - 4.0f * det;
        float delta = sqrtf(fmaxf(g, 1e-8f));
        feat0[p] = 0.5f * (tr + delta);
        feat1[p] = 0.5f * (tr - delta);
    }
    __builtin_amdgcn_sched_barrier(0);

    // ---- L1 ----
    float h1[A_PPT][16];
    unsigned m1[A_PPT];
#pragma unroll
    for (int p = 0; p < A_PPT; p++) m1[p] = 0u;
#pragma unroll
    for (int j = 0; j < 16; j++) {
        float wa = sW1[2 * j], wb = sW1[2 * j + 1], bb = sb1[j];
#pragma unroll
        for (int p = 0; p < A_PPT; p++) {
            float a = wa * feat0[p] + wb * feat1[p] + bb;
            m1[p] |= (a > 0.0f) ? (1u << j) : 0u;
            h1[p][j] = fmaxf(a, 0.0f);
        }
    }
    __builtin_amdgcn_sched_barrier(0);

    // ---- L2 (h1 dies at the end of this loop) ----
    float h2[A_PPT][16];
    unsigned m2[A_PPT];
#pragma unroll
    for (int p = 0; p < A_PPT; p++) m2[p] = 0u;
#pragma unroll
    for (int j = 0; j < 16; j++) {
        float4 w0 = W2r[4 * j], w1 = W2r[4 * j + 1], w2 = W2r[4 * j + 2], w3 = W2r[4 * j + 3];
        float bb = sb2[j];
#pragma unroll
        for (int p = 0; p < A_PPT; p++) {
            float a0 = w0.x * h1[p][0]  + w0.y * h1[p][1]  + w0.z * h1[p][2]  + w0.w * h1[p][3];
            float a1 = w1.x * h1[p][4]  + w1.y * h1[p][5]  + w1.z * h1[p][6]  + w1.w * h1[p][7];
            float a2 = w2.x * h1[p][8]  + w2.y * h1[p][9]  + w2.z * h1[p][10] + w2.w * h1[p][11];
            float a3 = w3.x * h1[p][12] + w3.y * h1[p][13] + w3.z * h1[p][14] + w3.w * h1[p][15];
            float a  = bb + ((a0 + a1) + (a2 + a3));
            m2[p] |= (a > 0.0f) ? (1u << j) : 0u;
            h2[p][j] = fmaxf(a, 0.0f);
        }
        __builtin_amdgcn_sched_barrier(0);
    }

    // ---- L3 fused with dh3 (h2 dies here; h3 never stored) ----
    float dh3[A_PPT][16];
#pragma unroll
    for (int j = 0; j < 16; j++) {
        float4 w0 = W3r[4 * j], w1 = W3r[4 * j + 1], w2 = W3r[4 * j + 2], w3 = W3r[4 * j + 3];
        float bb = sb3[j], w4j = sW4[j];
#pragma unroll
        for (int p = 0; p < A_PPT; p++) {
            float a0 = w0.x * h2[p][0]  + w0.y * h2[p][1]  + w0.z * h2[p][2]  + w0.w * h2[p][3];
            float a1 = w1.x * h2[p][4]  + w1.y * h2[p][5]  + w1.z * h2[p][6]  + w1.w * h2[p][7];
            float a2 = w2.x * h2[p][8]  + w2.y * h2[p][9]  + w2.z * h2[p][10] + w2.w * h2[p][11];
            float a3 = w3.x * h2[p][12] + w3.y * h2[p][13] + w3.z * h2[p][14] + w3.w * h2[p][15];
            float a = bb + ((a0 + a1) + (a2 + a3));
            dh3[p][j] = (a > 0.0f) ? w4j : 0.0f;
        }
        __builtin_amdgcn_sched_barrier(0);
    }

    // ---- Backward W3^T (dh3 dies here; gate via m2 bit test) ----
    float dh2[A_PPT][16];
#pragma unroll
    for (int kk = 0; kk < 16; kk++) {
        float4 w0 = W3Tr[4 * kk], w1 = W3Tr[4 * kk + 1], w2 = W3Tr[4 * kk + 2], w3 = W3Tr[4 * kk + 3];
#pragma unroll
        for (int p = 0; p < A_PPT; p++) {
            float a0 = w0.x * dh3[p][0]  + w0.y * dh3[p][1]  + w0.z * dh3[p][2]  + w0.w * dh3[p][3];
            float a1 = w1.x * dh3[p][4]  + w1.y * dh3[p][5]  + w1.z * dh3[p][6]  + w1.w * dh3[p][7];
            float a2 = w2.x * dh3[p][8]  + w2.y * dh3[p][9]  + w2.z * dh3[p][10] + w2.w * dh3[p][11];
            float a3 = w3.x * dh3[p][12] + w3.y * dh3[p][13] + w3.z * dh3[p][14] + w3.w * dh3[p][15];
            float a  = (a0 + a1) + (a2 + a3);
            dh2[p][kk] = ((m2[p] >> kk) & 1u) ? a : 0.0f;
        }
        __builtin_amdgcn_sched_barrier(0);
    }

    // ---- Backward W2^T + W1^T (gate via m1 bit test) ----
    float dfeat0[A_PPT], dfeat1[A_PPT];
#pragma unroll
    for (int p = 0; p < A_PPT; p++) { dfeat0[p] = 0.0f; dfeat1[p] = 0.0f; }

#pragma unroll
    for (int kk = 0; kk < 16; kk++) {
        float4 w0 = W2Tr[4 * kk], w1 = W2Tr[4 * kk + 1], w2 = W2Tr[4 * kk + 2], w3 = W2Tr[4 * kk + 3];
        float wa = sW1[2 * kk], wb = sW1[2 * kk + 1];
#pragma unroll
        for (int p = 0; p < A_PPT; p++) {
            float a0 = w0.x * dh2[p][0]  + w0.y * dh2[p][1]  + w0.z * dh2[p][2]  + w0.w * dh2[p][3];
            float a1 = w1.x * dh2[p][4]  + w1.y * dh2[p][5]  + w1.z * dh2[p][6]  + w1.w * dh2[p][7];
            float a2 = w2.x * dh2[p][8]  + w2.y * dh2[p][9]  + w2.z * dh2[p][10] + w2.w * dh2[p][11];
            float a3 = w3.x * dh2[p][12] + w3.y * dh2[p][13] + w3.z * dh2[p][14] + w3.w * dh2[p][15];
            float a  = (a0 + a1) + (a2 + a3);
            float dh1k = ((m1[p] >> kk) & 1u) ? a : 0.0f;
            dfeat0[p] += wa * dh1k;
            dfeat1[p] += wb * dh1k;
        }
        __builtin_amdgcn_sched_barrier(0);
    }

    // ---- Epilogue: reload x/C/F (L2/L3-hot), recompute, scatter ----
#pragma unroll
    for (int p = 0; p < A_PPT; p++) {
        if (!ok[p]) continue;
        int i = base + p * 256;

        float2 xi = x[i];
        float4 Ci = C[i];
        float4 Fi = F[i];

        float Fn00 = Fi.x + DTc * (Ci.x * Fi.x + Ci.y * Fi.z);
        float Fn01 = Fi.y + DTc * (Ci.x * Fi.y + Ci.y * Fi.w);
        float Fn10 = Fi.z + DTc * (Ci.z * Fi.x + Ci.w * Fi.z);
        float Fn11 = Fi.w + DTc * (Ci.z * Fi.y + Ci.w * Fi.w);

        float Cm00 = Fn00 * Fn00 + Fn10 * Fn10;
        float Cm01 = Fn00 * Fn01 + Fn10 * Fn11;
        float Cm11 = Fn01 * Fn01 + Fn11 * Fn11;

        float tr  = Cm00 + Cm11;
        float det = Cm00 * Cm11 - Cm01 * Cm01;
        float g   = tr * tr - 4.0f * det;
        float gate = (g > 1e-8f) ? 1.0f : 0.0f;
        float delta = sqrtf(fmaxf(g, 1e-8f));

        float half_sum  = 0.5f * (dfeat0[p] + dfeat1[p]);
        float half_diff = 0.5f * (dfeat0[p] - dfeat1[p]);
        float inv_delta = 1.0f / delta;
        float dtr  = half_sum + half_diff * tr * inv_delta * gate;
        float ddet = half_diff * (-2.0f) * inv_delta * gate;

        float S00 = 2.0f * (dtr + ddet * Cm11);
        float S11 = 2.0f * (dtr + ddet * Cm00);
        float S01 = -2.0f * ddet * Cm01;

        float dF00 = Fn00 * S00 + Fn01 * S01;
        float dF01 = Fn00 * S01 + Fn01 * S11;
        float dF10 = Fn10 * S00 + Fn11 * S01;
        float dF11 = Fn10 * S01 + Fn11 * S11;

        float a00 = STRESS_COEF * dF00 + P_MASSc * Ci.x;
        float a01 = STRESS_COEF * dF01 + P_MASSc * Ci.y;
        float a10 = STRESS_COEF * dF10 + P_MASSc * Ci.z;
        float a11 = STRESS_COEF * dF11 + P_MASSc * Ci.w;

        float2 vi = v[i];
        unsigned k = key[i];
        unsigned pos = binoff[k >> 20] + (k & 0xFFFFFu);

        recs[2 * (size_t)pos]     = make_float4(xi.x, xi.y, a00, a01);
        recs[2 * (size_t)pos + 1] = make_float4(a10, a11, P_MASSc * vi.x, P_MASSc * vi.y);
    }
}

// ---------------------------------------------------------------------------
// Gather-form grid build: one wave per grid node, register accumulate,
// butterfly reduce, fused grid update. No atomics.
// ---------------------------------------------------------------------------
__global__ __launch_bounds__(256) void grid_gather_kernel(
    const float4* __restrict__ recs, const unsigned* __restrict__ binoff,
    float2* __restrict__ gv)
{
    int wid  = threadIdx.x >> 6;
    int lane = threadIdx.x & 63;
    int node = blockIdx.x * 4 + wid;
    int gi = node >> 7;
    int gj = node & 127;

    const float gxx = (float)gi * DXc;
    const float gxy = (float)gj * DXc;

    float accx = 0.0f, accy = 0.0f, accm = 0.0f;

    int c0 = max(gj - 2, 0) >> 2;
    int c1 = min(gj, 127) >> 2;

#pragma unroll
    for (int r = 0; r < 3; r++) {
        int bx = gi - 2 + r;
        if (bx < 0 || bx > 127) continue;
        int lo = (int)binoff[bx * 32 + c0];
        int hi = (int)binoff[bx * 32 + c1 + 1];
        for (int k = lo + lane; k < hi; k += 64) {
            float4 r0 = recs[2 * (size_t)k];
            float4 r1 = recs[2 * (size_t)k + 1];

            float py = r0.y * INV_DX;
            int   by = (int)floorf(py - 0.5f);
            int   jj = gj - by;
            bool  ok = (jj >= 0) && (jj <= 2);

            float fy = py - (float)by;
            float fx = r0.x * INV_DX - (float)bx;

            float wx;
            if (r == 0)      wx = 0.5f * (fx - 0.5f) * (fx - 0.5f);   // ii = 2
            else if (r == 1) wx = 0.75f - (fx - 1.0f) * (fx - 1.0f);  // ii = 1
            else             wx = 0.5f * (1.5f - fx) * (1.5f - fx);   // ii = 0

            float wy0 = 0.5f * (1.5f - fy) * (1.5f - fy);
            float wy1 = 0.75f - (fy - 1.0f) * (fy - 1.0f);
            float wy2 = 0.5f * (fy - 0.5f) * (fy - 0.5f);
            float wy = (jj == 0) ? wy0 : ((jj == 1) ? wy1 : wy2);

            float wt = ok ? (wx * wy) : 0.0f;
            float dxp = gxx - r0.x;
            float dyp = gxy - r0.y;
            accx += wt * (r1.z + r0.z * dxp + r0.w * dyp);
            accy += wt * (r1.w + r1.x * dxp + r1.y * dyp);
            accm += wt * P_MASSc;
        }
    }

#pragma unroll
    for (int off = 32; off >= 1; off >>= 1) {
        accx += __shfl_xor(accx, off, 64);
        accy += __shfl_xor(accy, off, 64);
        accm += __shfl_xor(accm, off, 64);
    }

    if (lane == 0) {
        float vx = accx, vy = accy;
        if (accm > 0.0f) {
            float inv_m = 1.0f / accm;
            vx *= inv_m;
            vy *= inv_m;
        }
        vy -= DTc * GRAV;
        if (gi < 3)        vx = fmaxf(vx, 0.0f);
        if (gi >= NGc - 3) vx = fminf(vx, 0.0f);
        if (gj < 3)        vy = fmaxf(vy, 0.0f);
        if (gj >= NGc - 3) vy = fminf(vy, 0.0f);
        gv[node] = make_float2(vx, vy);
    }
}

// ---------------------------------------------------------------------------
// G2P (Fnew already written by stagea; no C/F reads here)
// ---------------------------------------------------------------------------
__global__ __launch_bounds__(256) void g2p_kernel(
    const float2* __restrict__ x, const float2* __restrict__ v,
    const int* __restrict__ material, const float* __restrict__ Jp,
    const float2* __restrict__ gv,
    float2* __restrict__ out_x, float2* __restrict__ out_v,
    float4* __restrict__ out_C,
    float* __restrict__ out_mat, float* __restrict__ out_Jp, int n)
{
    int i = blockIdx.x * 256 + threadIdx.x;
    if (i >= n) return;

    float2 xi = x[i];
    float2 vi = v[i];

    float px = xi.x * INV_DX, py = xi.y * INV_DX;
    int   bx = (int)floorf(px - 0.5f);
    int   by = (int)floorf(py - 0.5f);
    float fx = px - (float)bx;
    float fy = py - (float)by;
    float wxs[3] = {0.5f * (1.5f - fx) * (1.5f - fx),
                    0.75f - (fx - 1.0f) * (fx - 1.0f),
                    0.5f * (fx - 0.5f) * (fx - 0.5f)};
    float wys[3] = {0.5f * (1.5f - fy) * (1.5f - fy),
                    0.75f - (fy - 1.0f) * (fy - 1.0f),
                    0.5f * (fy - 0.5f) * (fy - 0.5f)};

    float accvx = 0.0f, accvy = 0.0f;
    float accC00 = 0.0f, accC01 = 0.0f, accC10 = 0.0f, accC11 = 0.0f;

#pragma unroll
    for (int ii = 0; ii < 3; ii++) {
        float gxx = (float)(bx + ii) * DXc;
#pragma unroll
        for (int jj = 0; jj < 3; jj++) {
            float wt = wxs[ii] * wys[jj];
            float2 gvn = gv[(bx + ii) * NGc + (by + jj)];
            float gxy = (float)(by + jj) * DXc;
            accvx  += wt * gvn.x;
            accvy  += wt * gvn.y;
            accC00 += wt * gvn.x * gxx;
            accC01 += wt * gvn.x * gxy;
            accC10 += wt * gvn.y * gxx;
            accC11 += wt * gvn.y * gxy;
        }
    }

    const float k4 = 4.0f * INV_DX * INV_DX;
    out_x[i]   = make_float2(xi.x + DTc * vi.x, xi.y + DTc * vi.y);
    out_v[i]   = make_float2(accvx, accvy);
    out_C[i]   = make_float4(k4 * (accC00 - accvx * xi.x),
                             k4 * (accC01 - accvx * xi.y),
                             k4 * (accC10 - accvy * xi.x),
                             k4 * (accC11 - accvy * xi.y));
    out_mat[i] = (float)material[i];
    out_Jp[i]  = Jp[i];
}

// ---------------------------------------------------------------------------
extern "C" void kernel_launch(void* const* d_in, const int* in_sizes, int n_in,
                              void* d_out, int out_size, void* d_ws, size_t ws_size,
                              hipStream_t stream)
{
    const float2* x  = (const float2*)d_in[0];
    const float2* v  = (const float2*)d_in[1];
    const float4* C  = (const float4*)d_in[2];
    const float4* F  = (const float4*)d_in[3];
    const int* material = (const int*)d_in[4];
    const float* Jp  = (const float*)d_in[5];
    const float* W1  = (const float*)d_in[8];
    const float* b1  = (const float*)d_in[9];
    const float* W2  = (const float*)d_in[10];
    const float* b2  = (const float*)d_in[11];
    const float* W3  = (const float*)d_in[12];
    const float* b3  = (const float*)d_in[13];
    const float* W4  = (const float*)d_in[14];

    const int n = in_sizes[0] / 2;

    // d_ws: gcnt (NBIN u32) + binoff (NBIN+1 u32) + gv (NCELL float2)
    unsigned* gcnt   = (unsigned*)d_ws;
    unsigned* binoff = gcnt + NBIN;
    float2*   gv     = (float2*)(binoff + NBIN + 1);

    float* out = (float*)d_out;
    float2* out_x   = (float2*)out;                    // 0..2N
    float2* out_v   = (float2*)(out + 2 * (size_t)n);  // 2N..4N
    float4* out_C   = (float4*)(out + 4 * (size_t)n);  // 4N..8N
    float4* out_F   = (float4*)(out + 8 * (size_t)n);  // 8N..12N  (written by stagea)
    float*  out_mat = out + 12 * (size_t)n;            // 12N..13N
    float*  out_Jp  = out + 13 * (size_t)n;            // 13N..14N

    // middle-phase scratch inside d_out (consumed before g2p overwrites):
    // recs occupies out[0..8N) = out_x/out_v/out_C regions, all written only
    // by g2p which runs after grid_gather has consumed recs.
    float4*   recs = (float4*)out;                     // 8N floats: 0..8N
    unsigned* key  = (unsigned*)out_mat;               // N u32:     12N..13N

    hipMemsetAsync(gcnt, 0, NBIN * sizeof(unsigned), stream);

    int s1_blocks = (n + S1_BLK * S1_PPT - 1) / (S1_BLK * S1_PPT);
    int blocks    = (n + 255) / 256;
    int a_blocks  = (n + 256 * A_PPT - 1) / (256 * A_PPT);
    bin_kernel<<<s1_blocks, S1_BLK, 0, stream>>>(x, key, gcnt, n);
    scan_kernel<<<1, 1024, 0, stream>>>(gcnt, binoff);
    stagea_kernel<<<a_blocks, 256, 0, stream>>>(x, v, C, F, W1, b1, W2, b2, W3, b3, W4,
                                                key, binoff, recs, out_F, n);
    grid_gather_kernel<<<NCELL / 4, 256, 0, stream>>>(recs, binoff, gv);
    g2p_kernel<<<blocks, 256, 0, stream>>>(x, v, material, Jp, gv,
                                           out_x, out_v, out_C, out_mat, out_Jp, n);
}

// Round 5
// 266.686 us; speedup vs baseline: 6.2865x; 6.0083x over previous
//
#include <hip/hip_runtime.h>
#include <math.h>

constexpr int   NGc    = 128;
constexpr int   NCELL  = NGc * NGc;
constexpr int   NBIN   = 128 * 32;          // bin = (bx, by>>2) : 4096
constexpr float DTc    = 1e-4f;
constexpr float DXc    = 1.0f / 128.0f;
constexpr float INV_DX = 128.0f;
constexpr float P_VOLc = (DXc * 0.5f) * (DXc * 0.5f);
constexpr float P_MASSc = P_VOLc * 1.0f;
constexpr float GRAV   = 9.8f;
constexpr float STRESS_COEF = -DTc * P_VOLc * 4.0f * INV_DX * INV_DX;

// ---------------------------------------------------------------------------
// S1: bin to 4096 bins (cell-row x col-group). LDS hist + local rank ->
// key = bin<<20 | pos_in_bin.
// ---------------------------------------------------------------------------
constexpr int S1_PPT = 16;
constexpr int S1_BLK = 1024;

__global__ __launch_bounds__(1024) void bin_kernel(
    const float2* __restrict__ x, unsigned* __restrict__ key,
    unsigned* __restrict__ gcnt, int n)
{
    __shared__ unsigned hist[NBIN];
#pragma unroll
    for (int j = 0; j < NBIN / S1_BLK; j++)
        hist[threadIdx.x + j * S1_BLK] = 0;
    __syncthreads();

    int base_i = blockIdx.x * (S1_BLK * S1_PPT);
    unsigned t_arr[S1_PPT], r_arr[S1_PPT];
#pragma unroll
    for (int k = 0; k < S1_PPT; k++) {
        int i = base_i + k * S1_BLK + threadIdx.x;
        unsigned t = 0, r = 0;
        if (i < n) {
            float2 xi = x[i];
            int bx = (int)floorf(xi.x * INV_DX - 0.5f);
            int by = (int)floorf(xi.y * INV_DX - 0.5f);
            t = (unsigned)(bx * 32 + (by >> 2));
            r = atomicAdd(&hist[t], 1u);
        }
        t_arr[k] = t; r_arr[k] = r;
    }
    __syncthreads();

#pragma unroll
    for (int j = 0; j < NBIN / S1_BLK; j++) {
        int b = threadIdx.x + j * S1_BLK;
        unsigned c = hist[b];
        __syncthreads();
        hist[b] = c ? atomicAdd(&gcnt[b], c) : 0u;
        __syncthreads();
    }

#pragma unroll
    for (int k = 0; k < S1_PPT; k++) {
        int i = base_i + k * S1_BLK + threadIdx.x;
        if (i < n)
            key[i] = (t_arr[k] << 20) | (hist[t_arr[k]] + r_arr[k]);
    }
}

// ---------------------------------------------------------------------------
// S2: exclusive scan over 4096 bin counts (single block, 4/thread) + sentinel
// ---------------------------------------------------------------------------
__global__ __launch_bounds__(1024) void scan_kernel(
    const unsigned* __restrict__ gcnt, unsigned* __restrict__ binoff)
{
    __shared__ unsigned s[1024];
    int t = threadIdx.x;
    unsigned v0 = gcnt[4 * t], v1 = gcnt[4 * t + 1];
    unsigned v2 = gcnt[4 * t + 2], v3 = gcnt[4 * t + 3];
    unsigned p = v0 + v1 + v2 + v3;
    s[t] = p;
    __syncthreads();
    for (int d = 1; d < 1024; d <<= 1) {
        unsigned add = (t >= d) ? s[t - d] : 0u;
        __syncthreads();
        s[t] += add;
        __syncthreads();
    }
    unsigned base = s[t] - p;
    binoff[4 * t]     = base;
    binoff[4 * t + 1] = base + v0;
    binoff[4 * t + 2] = base + v0 + v1;
    binoff[4 * t + 3] = base + v0 + v1 + v2;
    if (t == 1023) binoff[4096] = s[1023];
}

// ---------------------------------------------------------------------------
// Stage A v5: readlane-broadcast weights.
// R0 diagnosis: stagea is bound by the per-CU DS pipe (256 wave-uniform
// ds_read_b128 x ~12cyc x ~61 waves/CU ~= 78us == observed 80us); the FMA
// floor is ~14us. A_PPT amortization (R2-R4) died on register allocation.
// v5 removes the DS pipe from the equation entirely: weights live
// lane-distributed in 10 VGPRs (lane l holds W2[64r+l], W3[64r+l], plus a
// packed reg for W1/b*/W4); every use is v_readlane_b32 with a COMPILE-TIME
// lane index (loops fully unrolled), which the FMA consumes as its one legal
// SGPR operand. Transposed backward passes are free (different constant
// lane). No LDS, no __syncthreads, no extra per-thread state.
// Weight loads happen BEFORE the i>=n exit so readlane sources are written
// in every lane (v_readlane ignores EXEC).
// ---------------------------------------------------------------------------
#define RL(v, l) __int_as_float(__builtin_amdgcn_readlane(__float_as_int(v), (l)))

__global__ __launch_bounds__(256) void stagea_kernel(
    const float2* __restrict__ x, const float2* __restrict__ v,
    const float4* __restrict__ C, const float4* __restrict__ F,
    const float* __restrict__ W1, const float* __restrict__ b1,
    const float* __restrict__ W2, const float* __restrict__ b2,
    const float* __restrict__ W3, const float* __restrict__ b3,
    const float* __restrict__ W4,
    const unsigned* __restrict__ key, const unsigned* __restrict__ binoff,
    float4* __restrict__ recs, float4* __restrict__ out_F, int n)
{
    const int lane = threadIdx.x & 63;

    // lane-distributed weights (10 VGPRs/lane), loaded by ALL lanes
    float w2r[4], w3r[4];
#pragma unroll
    for (int r = 0; r < 4; r++) {
        w2r[r] = W2[r * 64 + lane];
        w3r[r] = W3[r * 64 + lane];
    }
    // wa: lanes 0..31 = W1[0..31], 32..47 = b1[0..15], 48..63 = W4[0..15]
    float wa = (lane < 32) ? W1[lane]
             : ((lane < 48) ? b1[lane - 32] : W4[lane - 48]);
    // wb: lanes 0..15 = b2[0..15], 16..31 = b3[0..15]
    float wb = (lane < 16) ? b2[lane]
             : ((lane < 32) ? b3[lane - 16] : 0.0f);

    int i = blockIdx.x * 256 + threadIdx.x;
    if (i >= n) return;

    float2 xi = x[i];
    float2 vi = v[i];
    float4 Ci = C[i];
    float4 Fi = F[i];

    float Fn00 = Fi.x + DTc * (Ci.x * Fi.x + Ci.y * Fi.z);
    float Fn01 = Fi.y + DTc * (Ci.x * Fi.y + Ci.y * Fi.w);
    float Fn10 = Fi.z + DTc * (Ci.z * Fi.x + Ci.w * Fi.z);
    float Fn11 = Fi.w + DTc * (Ci.z * Fi.y + Ci.w * Fi.w);

    out_F[i] = make_float4(Fn00, Fn01, Fn10, Fn11);

    float Cm00 = Fn00 * Fn00 + Fn10 * Fn10;
    float Cm01 = Fn00 * Fn01 + Fn10 * Fn11;
    float Cm11 = Fn01 * Fn01 + Fn11 * Fn11;

    float tr  = Cm00 + Cm11;
    float det = Cm00 * Cm11 - Cm01 * Cm01;
    float g   = tr * tr - 4.0f * det;
    float gate = (g > 1e-8f) ? 1.0f : 0.0f;
    float delta = sqrtf(fmaxf(g, 1e-8f));
    float feat0 = 0.5f * (tr + delta);
    float feat1 = 0.5f * (tr - delta);

    // ---- L1 ----
    float h1[16];
#pragma unroll
    for (int j = 0; j < 16; j++) {
        float a = RL(wa, 2 * j) * feat0 + RL(wa, 2 * j + 1) * feat1 + RL(wa, 32 + j);
        h1[j] = fmaxf(a, 0.0f);
    }

    // ---- L2: h2[j] = relu(b2[j] + sum_k W2[16j+k] h1[k]) ----
    float h2[16];
#pragma unroll
    for (int j = 0; j < 16; j++) {
        float a0 = RL(wb, j), a1 = 0.0f, a2 = 0.0f, a3 = 0.0f;
#pragma unroll
        for (int k = 0; k < 16; k += 4) {
            a0 += RL(w2r[(16 * j + k + 0) >> 6], (16 * j + k + 0) & 63) * h1[k + 0];
            a1 += RL(w2r[(16 * j + k + 1) >> 6], (16 * j + k + 1) & 63) * h1[k + 1];
            a2 += RL(w2r[(16 * j + k + 2) >> 6], (16 * j + k + 2) & 63) * h1[k + 2];
            a3 += RL(w2r[(16 * j + k + 3) >> 6], (16 * j + k + 3) & 63) * h1[k + 3];
        }
        h2[j] = fmaxf((a0 + a1) + (a2 + a3), 0.0f);
    }

    // ---- L3 fused with dh3: dh3[j] = (b3[j]+W3[j]·h2 > 0) ? W4[j] : 0 ----
    float dh3[16];
#pragma unroll
    for (int j = 0; j < 16; j++) {
        float a0 = RL(wb, 16 + j), a1 = 0.0f, a2 = 0.0f, a3 = 0.0f;
#pragma unroll
        for (int k = 0; k < 16; k += 4) {
            a0 += RL(w3r[(16 * j + k + 0) >> 6], (16 * j + k + 0) & 63) * h2[k + 0];
            a1 += RL(w3r[(16 * j + k + 1) >> 6], (16 * j + k + 1) & 63) * h2[k + 1];
            a2 += RL(w3r[(16 * j + k + 2) >> 6], (16 * j + k + 2) & 63) * h2[k + 2];
            a3 += RL(w3r[(16 * j + k + 3) >> 6], (16 * j + k + 3) & 63) * h2[k + 3];
        }
        float a = (a0 + a1) + (a2 + a3);
        dh3[j] = (a > 0.0f) ? RL(wa, 48 + j) : 0.0f;
    }

    // ---- Backward W3^T: dh2[k] = relu'(h2[k]) * sum_j W3[16j+k] dh3[j] ----
    float dh2[16];
#pragma unroll
    for (int kk = 0; kk < 16; kk++) {
        float a0 = 0.0f, a1 = 0.0f, a2 = 0.0f, a3 = 0.0f;
#pragma unroll
        for (int j = 0; j < 16; j += 4) {
            a0 += RL(w3r[(16 * (j + 0) + kk) >> 6], (16 * (j + 0) + kk) & 63) * dh3[j + 0];
            a1 += RL(w3r[(16 * (j + 1) + kk) >> 6], (16 * (j + 1) + kk) & 63) * dh3[j + 1];
            a2 += RL(w3r[(16 * (j + 2) + kk) >> 6], (16 * (j + 2) + kk) & 63) * dh3[j + 2];
            a3 += RL(w3r[(16 * (j + 3) + kk) >> 6], (16 * (j + 3) + kk) & 63) * dh3[j + 3];
        }
        float a = (a0 + a1) + (a2 + a3);
        dh2[kk] = (h2[kk] > 0.0f) ? a : 0.0f;
    }

    // ---- Backward W2^T + W1^T ----
    float dfeat0 = 0.0f, dfeat1 = 0.0f;
#pragma unroll
    for (int kk = 0; kk < 16; kk++) {
        float a0 = 0.0f, a1 = 0.0f, a2 = 0.0f, a3 = 0.0f;
#pragma unroll
        for (int j = 0; j < 16; j += 4) {
            a0 += RL(w2r[(16 * (j + 0) + kk) >> 6], (16 * (j + 0) + kk) & 63) * dh2[j + 0];
            a1 += RL(w2r[(16 * (j + 1) + kk) >> 6], (16 * (j + 1) + kk) & 63) * dh2[j + 1];
            a2 += RL(w2r[(16 * (j + 2) + kk) >> 6], (16 * (j + 2) + kk) & 63) * dh2[j + 2];
            a3 += RL(w2r[(16 * (j + 3) + kk) >> 6], (16 * (j + 3) + kk) & 63) * dh2[j + 3];
        }
        float a = (a0 + a1) + (a2 + a3);
        float dh1k = (h1[kk] > 0.0f) ? a : 0.0f;
        dfeat0 += RL(wa, 2 * kk) * dh1k;
        dfeat1 += RL(wa, 2 * kk + 1) * dh1k;
    }

    // ---- epilogue ----
    float half_sum  = 0.5f * (dfeat0 + dfeat1);
    float half_diff = 0.5f * (dfeat0 - dfeat1);
    float inv_delta = 1.0f / delta;
    float dtr  = half_sum + half_diff * tr * inv_delta * gate;
    float ddet = half_diff * (-2.0f) * inv_delta * gate;

    float S00 = 2.0f * (dtr + ddet * Cm11);
    float S11 = 2.0f * (dtr + ddet * Cm00);
    float S01 = -2.0f * ddet * Cm01;

    float dF00 = Fn00 * S00 + Fn01 * S01;
    float dF01 = Fn00 * S01 + Fn01 * S11;
    float dF10 = Fn10 * S00 + Fn11 * S01;
    float dF11 = Fn10 * S01 + Fn11 * S11;

    float a00 = STRESS_COEF * dF00 + P_MASSc * Ci.x;
    float a01 = STRESS_COEF * dF01 + P_MASSc * Ci.y;
    float a10 = STRESS_COEF * dF10 + P_MASSc * Ci.z;
    float a11 = STRESS_COEF * dF11 + P_MASSc * Ci.w;

    unsigned k = key[i];
    unsigned pos = binoff[k >> 20] + (k & 0xFFFFFu);

    recs[2 * (size_t)pos]     = make_float4(xi.x, xi.y, a00, a01);
    recs[2 * (size_t)pos + 1] = make_float4(a10, a11, P_MASSc * vi.x, P_MASSc * vi.y);
}

// ---------------------------------------------------------------------------
// Gather-form grid build: one wave per grid node, register accumulate,
// butterfly reduce, fused grid update. No atomics.
// ---------------------------------------------------------------------------
__global__ __launch_bounds__(256) void grid_gather_kernel(
    const float4* __restrict__ recs, const unsigned* __restrict__ binoff,
    float2* __restrict__ gv)
{
    int wid  = threadIdx.x >> 6;
    int lane = threadIdx.x & 63;
    int node = blockIdx.x * 4 + wid;
    int gi = node >> 7;
    int gj = node & 127;

    const float gxx = (float)gi * DXc;
    const float gxy = (float)gj * DXc;

    float accx = 0.0f, accy = 0.0f, accm = 0.0f;

    int c0 = max(gj - 2, 0) >> 2;
    int c1 = min(gj, 127) >> 2;

#pragma unroll
    for (int r = 0; r < 3; r++) {
        int bx = gi - 2 + r;
        if (bx < 0 || bx > 127) continue;
        int lo = (int)binoff[bx * 32 + c0];
        int hi = (int)binoff[bx * 32 + c1 + 1];
        for (int k = lo + lane; k < hi; k += 64) {
            float4 r0 = recs[2 * (size_t)k];
            float4 r1 = recs[2 * (size_t)k + 1];

            float py = r0.y * INV_DX;
            int   by = (int)floorf(py - 0.5f);
            int   jj = gj - by;
            bool  ok = (jj >= 0) && (jj <= 2);

            float fy = py - (float)by;
            float fx = r0.x * INV_DX - (float)bx;

            float wx;
            if (r == 0)      wx = 0.5f * (fx - 0.5f) * (fx - 0.5f);   // ii = 2
            else if (r == 1) wx = 0.75f - (fx - 1.0f) * (fx - 1.0f);  // ii = 1
            else             wx = 0.5f * (1.5f - fx) * (1.5f - fx);   // ii = 0

            float wy0 = 0.5f * (1.5f - fy) * (1.5f - fy);
            float wy1 = 0.75f - (fy - 1.0f) * (fy - 1.0f);
            float wy2 = 0.5f * (fy - 0.5f) * (fy - 0.5f);
            float wy = (jj == 0) ? wy0 : ((jj == 1) ? wy1 : wy2);

            float wt = ok ? (wx * wy) : 0.0f;
            float dxp = gxx - r0.x;
            float dyp = gxy - r0.y;
            accx += wt * (r1.z + r0.z * dxp + r0.w * dyp);
            accy += wt * (r1.w + r1.x * dxp + r1.y * dyp);
            accm += wt * P_MASSc;
        }
    }

#pragma unroll
    for (int off = 32; off >= 1; off >>= 1) {
        accx += __shfl_xor(accx, off, 64);
        accy += __shfl_xor(accy, off, 64);
        accm += __shfl_xor(accm, off, 64);
    }

    if (lane == 0) {
        float vx = accx, vy = accy;
        if (accm > 0.0f) {
            float inv_m = 1.0f / accm;
            vx *= inv_m;
            vy *= inv_m;
        }
        vy -= DTc * GRAV;
        if (gi < 3)        vx = fmaxf(vx, 0.0f);
        if (gi >= NGc - 3) vx = fminf(vx, 0.0f);
        if (gj < 3)        vy = fmaxf(vy, 0.0f);
        if (gj >= NGc - 3) vy = fminf(vy, 0.0f);
        gv[node] = make_float2(vx, vy);
    }
}

// ---------------------------------------------------------------------------
// G2P (Fnew already written by stagea; no C/F reads here)
// ---------------------------------------------------------------------------
__global__ __launch_bounds__(256) void g2p_kernel(
    const float2* __restrict__ x, const float2* __restrict__ v,
    const int* __restrict__ material, const float* __restrict__ Jp,
    const float2* __restrict__ gv,
    float2* __restrict__ out_x, float2* __restrict__ out_v,
    float4* __restrict__ out_C,
    float* __restrict__ out_mat, float* __restrict__ out_Jp, int n)
{
    int i = blockIdx.x * 256 + threadIdx.x;
    if (i >= n) return;

    float2 xi = x[i];
    float2 vi = v[i];

    float px = xi.x * INV_DX, py = xi.y * INV_DX;
    int   bx = (int)floorf(px - 0.5f);
    int   by = (int)floorf(py - 0.5f);
    float fx = px - (float)bx;
    float fy = py - (float)by;
    float wxs[3] = {0.5f * (1.5f - fx) * (1.5f - fx),
                    0.75f - (fx - 1.0f) * (fx - 1.0f),
                    0.5f * (fx - 0.5f) * (fx - 0.5f)};
    float wys[3] = {0.5f * (1.5f - fy) * (1.5f - fy),
                    0.75f - (fy - 1.0f) * (fy - 1.0f),
                    0.5f * (fy - 0.5f) * (fy - 0.5f)};

    float accvx = 0.0f, accvy = 0.0f;
    float accC00 = 0.0f, accC01 = 0.0f, accC10 = 0.0f, accC11 = 0.0f;

#pragma unroll
    for (int ii = 0; ii < 3; ii++) {
        float gxx = (float)(bx + ii) * DXc;
#pragma unroll
        for (int jj = 0; jj < 3; jj++) {
            float wt = wxs[ii] * wys[jj];
            float2 gvn = gv[(bx + ii) * NGc + (by + jj)];
            float gxy = (float)(by + jj) * DXc;
            accvx  += wt * gvn.x;
            accvy  += wt * gvn.y;
            accC00 += wt * gvn.x * gxx;
            accC01 += wt * gvn.x * gxy;
            accC10 += wt * gvn.y * gxx;
            accC11 += wt * gvn.y * gxy;
        }
    }

    const float k4 = 4.0f * INV_DX * INV_DX;
    out_x[i]   = make_float2(xi.x + DTc * vi.x, xi.y + DTc * vi.y);
    out_v[i]   = make_float2(accvx, accvy);
    out_C[i]   = make_float4(k4 * (accC00 - accvx * xi.x),
                             k4 * (accC01 - accvx * xi.y),
                             k4 * (accC10 - accvy * xi.x),
                             k4 * (accC11 - accvy * xi.y));
    out_mat[i] = (float)material[i];
    out_Jp[i]  = Jp[i];
}

// ---------------------------------------------------------------------------
extern "C" void kernel_launch(void* const* d_in, const int* in_sizes, int n_in,
                              void* d_out, int out_size, void* d_ws, size_t ws_size,
                              hipStream_t stream)
{
    const float2* x  = (const float2*)d_in[0];
    const float2* v  = (const float2*)d_in[1];
    const float4* C  = (const float4*)d_in[2];
    const float4* F  = (const float4*)d_in[3];
    const int* material = (const int*)d_in[4];
    const float* Jp  = (const float*)d_in[5];
    const float* W1  = (const float*)d_in[8];
    const float* b1  = (const float*)d_in[9];
    const float* W2  = (const float*)d_in[10];
    const float* b2  = (const float*)d_in[11];
    const float* W3  = (const float*)d_in[12];
    const float* b3  = (const float*)d_in[13];
    const float* W4  = (const float*)d_in[14];

    const int n = in_sizes[0] / 2;

    // d_ws: gcnt (NBIN u32) + binoff (NBIN+1 u32) + gv (NCELL float2)
    unsigned* gcnt   = (unsigned*)d_ws;
    unsigned* binoff = gcnt + NBIN;
    float2*   gv     = (float2*)(binoff + NBIN + 1);

    float* out = (float*)d_out;
    float2* out_x   = (float2*)out;                    // 0..2N
    float2* out_v   = (float2*)(out + 2 * (size_t)n);  // 2N..4N
    float4* out_C   = (float4*)(out + 4 * (size_t)n);  // 4N..8N
    float4* out_F   = (float4*)(out + 8 * (size_t)n);  // 8N..12N  (written by stagea)
    float*  out_mat = out + 12 * (size_t)n;            // 12N..13N
    float*  out_Jp  = out + 13 * (size_t)n;            // 13N..14N

    // middle-phase scratch inside d_out (consumed before g2p overwrites):
    // recs occupies out[0..8N) = out_x/out_v/out_C regions, all written only
    // by g2p which runs after grid_gather has consumed recs.
    float4*   recs = (float4*)out;                     // 8N floats: 0..8N
    unsigned* key  = (unsigned*)out_mat;               // N u32:     12N..13N

    hipMemsetAsync(gcnt, 0, NBIN * sizeof(unsigned), stream);

    int s1_blocks = (n + S1_BLK * S1_PPT - 1) / (S1_BLK * S1_PPT);
    int blocks    = (n + 255) / 256;
    bin_kernel<<<s1_blocks, S1_BLK, 0, stream>>>(x, key, gcnt, n);
    scan_kernel<<<1, 1024, 0, stream>>>(gcnt, binoff);
    stagea_kernel<<<blocks, 256, 0, stream>>>(x, v, C, F, W1, b1, W2, b2, W3, b3, W4,
                                              key, binoff, recs, out_F, n);
    grid_gather_kernel<<<NCELL / 4, 256, 0, stream>>>(recs, binoff, gv);
    g2p_kernel<<<blocks, 256, 0, stream>>>(x, v, material, Jp, gv,
                                           out_x, out_v, out_C, out_mat, out_Jp, n);
}

// Round 6
// 255.655 us; speedup vs baseline: 6.5578x; 1.0431x over previous
//
#include <hip/hip_runtime.h>
#include <math.h>

constexpr int   NGc    = 128;
constexpr int   NCELL  = NGc * NGc;
constexpr int   NBIN   = 128 * 128;         // exact-cell bins (bx, by)
constexpr float DTc    = 1e-4f;
constexpr float DXc    = 1.0f / 128.0f;
constexpr float INV_DX = 128.0f;
constexpr float P_VOLc = (DXc * 0.5f) * (DXc * 0.5f);
constexpr float P_MASSc = P_VOLc * 1.0f;
constexpr float GRAV   = 9.8f;
constexpr float STRESS_COEF = -DTc * P_VOLc * 4.0f * INV_DX * INV_DX;

// key = bin<<18 | rank  (bin < 16384 -> 14 bits; per-bin rank << 2^18)
constexpr int KEY_SHIFT = 18;
constexpr unsigned KEY_MASK = (1u << KEY_SHIFT) - 1u;

// ---------------------------------------------------------------------------
// S1: bin to 16384 exact-cell bins. LDS hist (64KB) + local rank ->
// key = bin<<18 | pos_in_bin.
// ---------------------------------------------------------------------------
constexpr int S1_PPT = 16;
constexpr int S1_BLK = 1024;

__global__ __launch_bounds__(1024) void bin_kernel(
    const float2* __restrict__ x, unsigned* __restrict__ key,
    unsigned* __restrict__ gcnt, int n)
{
    __shared__ unsigned hist[NBIN];
#pragma unroll
    for (int j = 0; j < NBIN / S1_BLK; j++)
        hist[threadIdx.x + j * S1_BLK] = 0;
    __syncthreads();

    int base_i = blockIdx.x * (S1_BLK * S1_PPT);
    unsigned t_arr[S1_PPT], r_arr[S1_PPT];
#pragma unroll
    for (int k = 0; k < S1_PPT; k++) {
        int i = base_i + k * S1_BLK + threadIdx.x;
        unsigned t = 0, r = 0;
        if (i < n) {
            float2 xi = x[i];
            int bx = (int)floorf(xi.x * INV_DX - 0.5f);
            int by = (int)floorf(xi.y * INV_DX - 0.5f);
            t = (unsigned)(bx * 128 + by);
            r = atomicAdd(&hist[t], 1u);
        }
        t_arr[k] = t; r_arr[k] = r;
    }
    __syncthreads();

#pragma unroll
    for (int j = 0; j < NBIN / S1_BLK; j++) {
        int b = threadIdx.x + j * S1_BLK;
        unsigned c = hist[b];
        __syncthreads();
        hist[b] = c ? atomicAdd(&gcnt[b], c) : 0u;
        __syncthreads();
    }

#pragma unroll
    for (int k = 0; k < S1_PPT; k++) {
        int i = base_i + k * S1_BLK + threadIdx.x;
        if (i < n)
            key[i] = (t_arr[k] << KEY_SHIFT) | (hist[t_arr[k]] + r_arr[k]);
    }
}

// ---------------------------------------------------------------------------
// S2: exclusive scan over 16384 bin counts (single block, 16/thread)
// ---------------------------------------------------------------------------
__global__ __launch_bounds__(1024) void scan_kernel(
    const unsigned* __restrict__ gcnt, unsigned* __restrict__ binoff)
{
    __shared__ unsigned s[1024];
    int t = threadIdx.x;
    unsigned v[16];
    unsigned p = 0;
#pragma unroll
    for (int k = 0; k < 16; k++) { v[k] = gcnt[16 * t + k]; p += v[k]; }
    s[t] = p;
    __syncthreads();
    for (int d = 1; d < 1024; d <<= 1) {
        unsigned add = (t >= d) ? s[t - d] : 0u;
        __syncthreads();
        s[t] += add;
        __syncthreads();
    }
    unsigned base = s[t] - p;
#pragma unroll
    for (int k = 0; k < 16; k++) { binoff[16 * t + k] = base; base += v[k]; }
    if (t == 1023) binoff[NBIN] = s[1023];
}

// ---------------------------------------------------------------------------
// Stage A v5 (proven R5): readlane-broadcast weights. Weights live
// lane-distributed in 10 VGPRs; every use is v_readlane_b32 with a
// compile-time lane index feeding the FMA's legal SGPR operand. No LDS,
// no syncthreads, no DS pipe. Transposed backward passes free.
// Weight loads happen BEFORE the i>=n exit (readlane ignores EXEC).
// ---------------------------------------------------------------------------
#define RL(v, l) __int_as_float(__builtin_amdgcn_readlane(__float_as_int(v), (l)))

__global__ __launch_bounds__(256) void stagea_kernel(
    const float2* __restrict__ x, const float2* __restrict__ v,
    const float4* __restrict__ C, const float4* __restrict__ F,
    const float* __restrict__ W1, const float* __restrict__ b1,
    const float* __restrict__ W2, const float* __restrict__ b2,
    const float* __restrict__ W3, const float* __restrict__ b3,
    const float* __restrict__ W4,
    const unsigned* __restrict__ key, const unsigned* __restrict__ binoff,
    float4* __restrict__ recs, float4* __restrict__ out_F, int n)
{
    const int lane = threadIdx.x & 63;

    // lane-distributed weights (10 VGPRs/lane), loaded by ALL lanes
    float w2r[4], w3r[4];
#pragma unroll
    for (int r = 0; r < 4; r++) {
        w2r[r] = W2[r * 64 + lane];
        w3r[r] = W3[r * 64 + lane];
    }
    // wa: lanes 0..31 = W1[0..31], 32..47 = b1[0..15], 48..63 = W4[0..15]
    float wa = (lane < 32) ? W1[lane]
             : ((lane < 48) ? b1[lane - 32] : W4[lane - 48]);
    // wb: lanes 0..15 = b2[0..15], 16..31 = b3[0..15]
    float wb = (lane < 16) ? b2[lane]
             : ((lane < 32) ? b3[lane - 16] : 0.0f);

    int i = blockIdx.x * 256 + threadIdx.x;
    if (i >= n) return;

    float2 xi = x[i];
    float2 vi = v[i];
    float4 Ci = C[i];
    float4 Fi = F[i];

    float Fn00 = Fi.x + DTc * (Ci.x * Fi.x + Ci.y * Fi.z);
    float Fn01 = Fi.y + DTc * (Ci.x * Fi.y + Ci.y * Fi.w);
    float Fn10 = Fi.z + DTc * (Ci.z * Fi.x + Ci.w * Fi.z);
    float Fn11 = Fi.w + DTc * (Ci.z * Fi.y + Ci.w * Fi.w);

    out_F[i] = make_float4(Fn00, Fn01, Fn10, Fn11);

    float Cm00 = Fn00 * Fn00 + Fn10 * Fn10;
    float Cm01 = Fn00 * Fn01 + Fn10 * Fn11;
    float Cm11 = Fn01 * Fn01 + Fn11 * Fn11;

    float tr  = Cm00 + Cm11;
    float det = Cm00 * Cm11 - Cm01 * Cm01;
    float g   = tr * tr - 4.0f * det;
    float gate = (g > 1e-8f) ? 1.0f : 0.0f;
    float delta = sqrtf(fmaxf(g, 1e-8f));
    float feat0 = 0.5f * (tr + delta);
    float feat1 = 0.5f * (tr - delta);

    // ---- L1 ----
    float h1[16];
#pragma unroll
    for (int j = 0; j < 16; j++) {
        float a = RL(wa, 2 * j) * feat0 + RL(wa, 2 * j + 1) * feat1 + RL(wa, 32 + j);
        h1[j] = fmaxf(a, 0.0f);
    }

    // ---- L2: h2[j] = relu(b2[j] + sum_k W2[16j+k] h1[k]) ----
    float h2[16];
#pragma unroll
    for (int j = 0; j < 16; j++) {
        float a0 = RL(wb, j), a1 = 0.0f, a2 = 0.0f, a3 = 0.0f;
#pragma unroll
        for (int k = 0; k < 16; k += 4) {
            a0 += RL(w2r[(16 * j + k + 0) >> 6], (16 * j + k + 0) & 63) * h1[k + 0];
            a1 += RL(w2r[(16 * j + k + 1) >> 6], (16 * j + k + 1) & 63) * h1[k + 1];
            a2 += RL(w2r[(16 * j + k + 2) >> 6], (16 * j + k + 2) & 63) * h1[k + 2];
            a3 += RL(w2r[(16 * j + k + 3) >> 6], (16 * j + k + 3) & 63) * h1[k + 3];
        }
        h2[j] = fmaxf((a0 + a1) + (a2 + a3), 0.0f);
    }

    // ---- L3 fused with dh3: dh3[j] = (b3[j]+W3[j]·h2 > 0) ? W4[j] : 0 ----
    float dh3[16];
#pragma unroll
    for (int j = 0; j < 16; j++) {
        float a0 = RL(wb, 16 + j), a1 = 0.0f, a2 = 0.0f, a3 = 0.0f;
#pragma unroll
        for (int k = 0; k < 16; k += 4) {
            a0 += RL(w3r[(16 * j + k + 0) >> 6], (16 * j + k + 0) & 63) * h2[k + 0];
            a1 += RL(w3r[(16 * j + k + 1) >> 6], (16 * j + k + 1) & 63) * h2[k + 1];
            a2 += RL(w3r[(16 * j + k + 2) >> 6], (16 * j + k + 2) & 63) * h2[k + 2];
            a3 += RL(w3r[(16 * j + k + 3) >> 6], (16 * j + k + 3) & 63) * h2[k + 3];
        }
        float a = (a0 + a1) + (a2 + a3);
        dh3[j] = (a > 0.0f) ? RL(wa, 48 + j) : 0.0f;
    }

    // ---- Backward W3^T: dh2[k] = relu'(h2[k]) * sum_j W3[16j+k] dh3[j] ----
    float dh2[16];
#pragma unroll
    for (int kk = 0; kk < 16; kk++) {
        float a0 = 0.0f, a1 = 0.0f, a2 = 0.0f, a3 = 0.0f;
#pragma unroll
        for (int j = 0; j < 16; j += 4) {
            a0 += RL(w3r[(16 * (j + 0) + kk) >> 6], (16 * (j + 0) + kk) & 63) * dh3[j + 0];
            a1 += RL(w3r[(16 * (j + 1) + kk) >> 6], (16 * (j + 1) + kk) & 63) * dh3[j + 1];
            a2 += RL(w3r[(16 * (j + 2) + kk) >> 6], (16 * (j + 2) + kk) & 63) * dh3[j + 2];
            a3 += RL(w3r[(16 * (j + 3) + kk) >> 6], (16 * (j + 3) + kk) & 63) * dh3[j + 3];
        }
        float a = (a0 + a1) + (a2 + a3);
        dh2[kk] = (h2[kk] > 0.0f) ? a : 0.0f;
    }

    // ---- Backward W2^T + W1^T ----
    float dfeat0 = 0.0f, dfeat1 = 0.0f;
#pragma unroll
    for (int kk = 0; kk < 16; kk++) {
        float a0 = 0.0f, a1 = 0.0f, a2 = 0.0f, a3 = 0.0f;
#pragma unroll
        for (int j = 0; j < 16; j += 4) {
            a0 += RL(w2r[(16 * (j + 0) + kk) >> 6], (16 * (j + 0) + kk) & 63) * dh2[j + 0];
            a1 += RL(w2r[(16 * (j + 1) + kk) >> 6], (16 * (j + 1) + kk) & 63) * dh2[j + 1];
            a2 += RL(w2r[(16 * (j + 2) + kk) >> 6], (16 * (j + 2) + kk) & 63) * dh2[j + 2];
            a3 += RL(w2r[(16 * (j + 3) + kk) >> 6], (16 * (j + 3) + kk) & 63) * dh2[j + 3];
        }
        float a = (a0 + a1) + (a2 + a3);
        float dh1k = (h1[kk] > 0.0f) ? a : 0.0f;
        dfeat0 += RL(wa, 2 * kk) * dh1k;
        dfeat1 += RL(wa, 2 * kk + 1) * dh1k;
    }

    // ---- epilogue ----
    float half_sum  = 0.5f * (dfeat0 + dfeat1);
    float half_diff = 0.5f * (dfeat0 - dfeat1);
    float inv_delta = 1.0f / delta;
    float dtr  = half_sum + half_diff * tr * inv_delta * gate;
    float ddet = half_diff * (-2.0f) * inv_delta * gate;

    float S00 = 2.0f * (dtr + ddet * Cm11);
    float S11 = 2.0f * (dtr + ddet * Cm00);
    float S01 = -2.0f * ddet * Cm01;

    float dF00 = Fn00 * S00 + Fn01 * S01;
    float dF01 = Fn00 * S01 + Fn01 * S11;
    float dF10 = Fn10 * S00 + Fn11 * S01;
    float dF11 = Fn10 * S01 + Fn11 * S11;

    float a00 = STRESS_COEF * dF00 + P_MASSc * Ci.x;
    float a01 = STRESS_COEF * dF01 + P_MASSc * Ci.y;
    float a10 = STRESS_COEF * dF10 + P_MASSc * Ci.z;
    float a11 = STRESS_COEF * dF11 + P_MASSc * Ci.w;

    unsigned k = key[i];
    unsigned pos = binoff[k >> KEY_SHIFT] + (k & KEY_MASK);

    recs[2 * (size_t)pos]     = make_float4(xi.x, xi.y, a00, a01);
    recs[2 * (size_t)pos + 1] = make_float4(a10, a11, P_MASSc * vi.x, P_MASSc * vi.y);
}

// ---------------------------------------------------------------------------
// Gather-form grid build with exact-cell bins: one wave per node reads
// exactly rows gi-2..gi x cells gj-2..gj (contiguous binoff range per row).
// Every loaded record is a guaranteed contributor (no ok-filter):
// 9 cell-reads/node vs 18 with 4-cell bins -> half the record traffic+VALU.
// ---------------------------------------------------------------------------
__global__ __launch_bounds__(256) void grid_gather_kernel(
    const float4* __restrict__ recs, const unsigned* __restrict__ binoff,
    float2* __restrict__ gv)
{
    int wid  = threadIdx.x >> 6;
    int lane = threadIdx.x & 63;
    int node = blockIdx.x * 4 + wid;
    int gi = node >> 7;
    int gj = node & 127;

    const float gxx = (float)gi * DXc;
    const float gxy = (float)gj * DXc;

    float accx = 0.0f, accy = 0.0f, accm = 0.0f;

    int j0 = max(gj - 2, 0);

#pragma unroll
    for (int r = 0; r < 3; r++) {
        int bx = gi - 2 + r;
        if (bx < 0 || bx > 127) continue;
        int lo = (int)binoff[bx * 128 + j0];
        int hi = (int)binoff[bx * 128 + gj + 1];
        for (int k = lo + lane; k < hi; k += 64) {
            float4 r0 = recs[2 * (size_t)k];
            float4 r1 = recs[2 * (size_t)k + 1];

            float py = r0.y * INV_DX;
            int   by = (int)floorf(py - 0.5f);
            int   jj = gj - by;                     // guaranteed 0..2

            float fy = py - (float)by;
            float fx = r0.x * INV_DX - (float)bx;

            float wx;
            if (r == 0)      wx = 0.5f * (fx - 0.5f) * (fx - 0.5f);   // ii = 2
            else if (r == 1) wx = 0.75f - (fx - 1.0f) * (fx - 1.0f);  // ii = 1
            else             wx = 0.5f * (1.5f - fx) * (1.5f - fx);   // ii = 0

            float wy0 = 0.5f * (1.5f - fy) * (1.5f - fy);
            float wy1 = 0.75f - (fy - 1.0f) * (fy - 1.0f);
            float wy2 = 0.5f * (fy - 0.5f) * (fy - 0.5f);
            float wy = (jj == 0) ? wy0 : ((jj == 1) ? wy1 : wy2);

            float wt = wx * wy;
            float dxp = gxx - r0.x;
            float dyp = gxy - r0.y;
            accx += wt * (r1.z + r0.z * dxp + r0.w * dyp);
            accy += wt * (r1.w + r1.x * dxp + r1.y * dyp);
            accm += wt * P_MASSc;
        }
    }

#pragma unroll
    for (int off = 32; off >= 1; off >>= 1) {
        accx += __shfl_xor(accx, off, 64);
        accy += __shfl_xor(accy, off, 64);
        accm += __shfl_xor(accm, off, 64);
    }

    if (lane == 0) {
        float vx = accx, vy = accy;
        if (accm > 0.0f) {
            float inv_m = 1.0f / accm;
            vx *= inv_m;
            vy *= inv_m;
        }
        vy -= DTc * GRAV;
        if (gi < 3)        vx = fmaxf(vx, 0.0f);
        if (gi >= NGc - 3) vx = fminf(vx, 0.0f);
        if (gj < 3)        vy = fmaxf(vy, 0.0f);
        if (gj >= NGc - 3) vy = fminf(vy, 0.0f);
        gv[node] = make_float2(vx, vy);
    }
}

// ---------------------------------------------------------------------------
// G2P (Fnew already written by stagea; no C/F reads here)
// ---------------------------------------------------------------------------
__global__ __launch_bounds__(256) void g2p_kernel(
    const float2* __restrict__ x, const float2* __restrict__ v,
    const int* __restrict__ material, const float* __restrict__ Jp,
    const float2* __restrict__ gv,
    float2* __restrict__ out_x, float2* __restrict__ out_v,
    float4* __restrict__ out_C,
    float* __restrict__ out_mat, float* __restrict__ out_Jp, int n)
{
    int i = blockIdx.x * 256 + threadIdx.x;
    if (i >= n) return;

    float2 xi = x[i];
    float2 vi = v[i];

    float px = xi.x * INV_DX, py = xi.y * INV_DX;
    int   bx = (int)floorf(px - 0.5f);
    int   by = (int)floorf(py - 0.5f);
    float fx = px - (float)bx;
    float fy = py - (float)by;
    float wxs[3] = {0.5f * (1.5f - fx) * (1.5f - fx),
                    0.75f - (fx - 1.0f) * (fx - 1.0f),
                    0.5f * (fx - 0.5f) * (fx - 0.5f)};
    float wys[3] = {0.5f * (1.5f - fy) * (1.5f - fy),
                    0.75f - (fy - 1.0f) * (fy - 1.0f),
                    0.5f * (fy - 0.5f) * (fy - 0.5f)};

    float accvx = 0.0f, accvy = 0.0f;
    float accC00 = 0.0f, accC01 = 0.0f, accC10 = 0.0f, accC11 = 0.0f;

#pragma unroll
    for (int ii = 0; ii < 3; ii++) {
        float gxx = (float)(bx + ii) * DXc;
#pragma unroll
        for (int jj = 0; jj < 3; jj++) {
            float wt = wxs[ii] * wys[jj];
            float2 gvn = gv[(bx + ii) * NGc + (by + jj)];
            float gxy = (float)(by + jj) * DXc;
            accvx  += wt * gvn.x;
            accvy  += wt * gvn.y;
            accC00 += wt * gvn.x * gxx;
            accC01 += wt * gvn.x * gxy;
            accC10 += wt * gvn.y * gxx;
            accC11 += wt * gvn.y * gxy;
        }
    }

    const float k4 = 4.0f * INV_DX * INV_DX;
    out_x[i]   = make_float2(xi.x + DTc * vi.x, xi.y + DTc * vi.y);
    out_v[i]   = make_float2(accvx, accvy);
    out_C[i]   = make_float4(k4 * (accC00 - accvx * xi.x),
                             k4 * (accC01 - accvx * xi.y),
                             k4 * (accC10 - accvy * xi.x),
                             k4 * (accC11 - accvy * xi.y));
    out_mat[i] = (float)material[i];
    out_Jp[i]  = Jp[i];
}

// ---------------------------------------------------------------------------
extern "C" void kernel_launch(void* const* d_in, const int* in_sizes, int n_in,
                              void* d_out, int out_size, void* d_ws, size_t ws_size,
                              hipStream_t stream)
{
    const float2* x  = (const float2*)d_in[0];
    const float2* v  = (const float2*)d_in[1];
    const float4* C  = (const float4*)d_in[2];
    const float4* F  = (const float4*)d_in[3];
    const int* material = (const int*)d_in[4];
    const float* Jp  = (const float*)d_in[5];
    const float* W1  = (const float*)d_in[8];
    const float* b1  = (const float*)d_in[9];
    const float* W2  = (const float*)d_in[10];
    const float* b2  = (const float*)d_in[11];
    const float* W3  = (const float*)d_in[12];
    const float* b3  = (const float*)d_in[13];
    const float* W4  = (const float*)d_in[14];

    const int n = in_sizes[0] / 2;

    // d_ws: gv (NCELL float2, 128KB) — read by g2p so it cannot live in d_out
    float2* gv = (float2*)d_ws;

    float* out = (float*)d_out;
    float2* out_x   = (float2*)out;                    // 0..2N
    float2* out_v   = (float2*)(out + 2 * (size_t)n);  // 2N..4N
    float4* out_C   = (float4*)(out + 4 * (size_t)n);  // 4N..8N
    float4* out_F   = (float4*)(out + 8 * (size_t)n);  // 8N..12N  (written by stagea)
    float*  out_mat = out + 12 * (size_t)n;            // 12N..13N
    float*  out_Jp  = out + 13 * (size_t)n;            // 13N..14N

    // middle-phase scratch inside d_out (consumed before g2p overwrites):
    //  recs   at out[0..8N)      (g2p writes these regions last)
    //  key    at out[12N..13N)   (out_mat, written by g2p last)
    //  gcnt+binoff (16384+16385 u32 = 131KB) at out[13N..)  (out_Jp region,
    //  consumed by stagea/gather before g2p writes out_Jp)
    float4*   recs   = (float4*)out;
    unsigned* key    = (unsigned*)out_mat;
    unsigned* gcnt   = (unsigned*)(out + 13 * (size_t)n);
    unsigned* binoff = gcnt + NBIN;

    hipMemsetAsync(gcnt, 0, NBIN * sizeof(unsigned), stream);

    int s1_blocks = (n + S1_BLK * S1_PPT - 1) / (S1_BLK * S1_PPT);
    int blocks    = (n + 255) / 256;
    bin_kernel<<<s1_blocks, S1_BLK, 0, stream>>>(x, key, gcnt, n);
    scan_kernel<<<1, 1024, 0, stream>>>(gcnt, binoff);
    stagea_kernel<<<blocks, 256, 0, stream>>>(x, v, C, F, W1, b1, W2, b2, W3, b3, W4,
                                              key, binoff, recs, out_F, n);
    grid_gather_kernel<<<NCELL / 4, 256, 0, stream>>>(recs, binoff, gv);
    g2p_kernel<<<blocks, 256, 0, stream>>>(x, v, material, Jp, gv,
                                           out_x, out_v, out_C, out_mat, out_Jp, n);
}